// Round 3
// baseline (689.236 us; speedup 1.0000x reference)
//
#include <hip/hip_runtime.h>

// Problem constants: B=8, T=256, U=64, D=640, V=1024
//   enc  [8,256,640] f32, pred [8,64,640] f32, W [1024,1280] f32, bias [1024] f32
//   out  = [131072,1024] f32 joint ++ [8] source_lengths ++ [8] target_lengths
//
// Factorization: relu(concat(e,p)) @ W^T = relu(e)@W[:, :640]^T + relu(p)@W[:, 640:]^T
//   P[bu, v] = sum_d relu(pred[bu,d]) * W[v,640+d]              (512 x 1024, kernel 1)
//   out[bt*64+u, v] = (E[bt,v]+bias[v]) + P[(bt>>8)*64+u, v]    (fused kernel 2: E in registers)

// ---------------- Kernel 1: P = relu(pred) @ W2^T (no bias) ----------------
#define PBM 64
#define PBN 64
#define PBK 16
#define PPAD 4

__global__ __launch_bounds__(256) void p_gemm_kernel(
    const float* __restrict__ pred,  // [512, 640]
    const float* __restrict__ W,     // [1024, 1280]
    float* __restrict__ P)           // [512, 1024]
{
    __shared__ float As[PBK][PBM + PPAD];
    __shared__ float Bs[PBK][PBN + PPAD];

    const int tid  = threadIdx.x;
    const int row0 = blockIdx.y * PBM;
    const int col0 = blockIdx.x * PBN;

    const int lm = tid >> 2;
    const int lk = (tid & 3) * 4;
    const int tx = tid & 15;
    const int ty = tid >> 4;

    float acc[4][4];
    #pragma unroll
    for (int i = 0; i < 4; ++i)
        #pragma unroll
        for (int j = 0; j < 4; ++j) acc[i][j] = 0.f;

    for (int k0 = 0; k0 < 640; k0 += PBK) {
        float4 a4 = *(const float4*)(pred + (size_t)(row0 + lm) * 640 + k0 + lk);
        float4 b4 = *(const float4*)(W + (size_t)(col0 + lm) * 1280 + 640 + k0 + lk);
        As[lk + 0][lm] = fmaxf(a4.x, 0.f);
        As[lk + 1][lm] = fmaxf(a4.y, 0.f);
        As[lk + 2][lm] = fmaxf(a4.z, 0.f);
        As[lk + 3][lm] = fmaxf(a4.w, 0.f);
        Bs[lk + 0][lm] = b4.x;
        Bs[lk + 1][lm] = b4.y;
        Bs[lk + 2][lm] = b4.z;
        Bs[lk + 3][lm] = b4.w;
        __syncthreads();

        #pragma unroll
        for (int k = 0; k < PBK; ++k) {
            float4 av = *(const float4*)&As[k][ty * 4];
            float4 bv = *(const float4*)&Bs[k][tx * 4];
            float ar[4] = {av.x, av.y, av.z, av.w};
            float br[4] = {bv.x, bv.y, bv.z, bv.w};
            #pragma unroll
            for (int i = 0; i < 4; ++i)
                #pragma unroll
                for (int j = 0; j < 4; ++j)
                    acc[i][j] = fmaf(ar[i], br[j], acc[i][j]);
        }
        __syncthreads();
    }

    #pragma unroll
    for (int i = 0; i < 4; ++i) {
        float4 o;
        o.x = acc[i][0]; o.y = acc[i][1]; o.z = acc[i][2]; o.w = acc[i][3];
        *(float4*)(P + (size_t)(row0 + ty * 4 + i) * 1024 + col0 + tx * 4) = o;
    }
}

// ---------------- Kernel 2: fused E-GEMM + broadcast-add (v2) ----------------
// Tile 32 bt x 256 v, 256 threads (4 waves), micro 8x4. 256 blocks = 1/CU exact.
// grid dim3(4,64): blockIdx.x = vtile -> XCD id (block%8) pins vtile parity class,
//   so each XCD's L2 holds ONE 655 KB W-slab + P (2 MB) = 2.7 MB < 4 MB.
// Phase A: K-loop with register prefetch (T14): issue next K-tile's global loads
//   right after the staging barrier; compute hides the L2 latency.
//   Ws stored [k][v] stride 260: staging writes 2-way bank alias (free, m136);
//   compute B-read = 1 contiguous ds_read_b128; A-reads wave-uniform broadcasts.
// Phase B: stream out = E(+bias) + P with plain float4 stores (write-BW bound).

#define EBM 32
#define EBN 256
#define EBK 16
#define WSS 260   // 256 + 4 pad: bank = (4k+v)%32 for staging writes -> 2-way

__global__ __launch_bounds__(256) void e_fused_kernel(
    const float* __restrict__ enc,   // [2048, 640]
    const float* __restrict__ W,     // [1024, 1280]
    const float* __restrict__ bias,  // [1024]
    const float* __restrict__ P,     // [512, 1024]
    float* __restrict__ out)         // [131072, 1024]
{
    __shared__ float Ws[EBK * WSS];      // [k][v] padded, 16.6 KB
    __shared__ float As[EBK * EBM];      // [k][row], 2 KB

    const int t   = threadIdx.x;         // 0..255
    const int vt  = blockIdx.x;          // 0..3
    const int tt  = blockIdx.y;          // 0..63
    const int bt0 = tt * EBM;            // 32-row tiles never straddle batches (256%32==0)
    const int v0  = vt * EBN;
    const int b   = bt0 >> 8;

    // compute mapping: wave = ty (rows ty*8..+7), lane = tx (cols tx*4..+3)
    const int tx = t & 63;
    const int ty = t >> 6;
    const int l4 = tx * 4;

    // staging mapping (W): 4 lanes per row, 64 B per row per instr (16 lines/instr)
    const int svv = t >> 2;              // 0..63, + rep*64
    const int skc = (t & 3) * 4;         // k-chunk 0,4,8,12
    // staging mapping (enc): threads 0..127, one float4 each
    const int arow = t & 31;
    const int akq  = (t >> 5) & 3;

    float4 wq[4];
    float4 aq = make_float4(0.f, 0.f, 0.f, 0.f);

    // prefetch K-tile 0
    #pragma unroll
    for (int rep = 0; rep < 4; ++rep)
        wq[rep] = *(const float4*)(W + (size_t)(v0 + rep * 64 + svv) * 1280 + skc);
    if (t < 128)
        aq = *(const float4*)(enc + (size_t)(bt0 + arow) * 640 + akq * 4);

    float acc[8][4];
    #pragma unroll
    for (int i = 0; i < 8; ++i)
        #pragma unroll
        for (int j = 0; j < 4; ++j) acc[i][j] = 0.f;

    for (int kt = 0; kt < 40; ++kt) {
        __syncthreads();                 // previous compute done before overwrite
        #pragma unroll
        for (int rep = 0; rep < 4; ++rep) {
            const int vv = rep * 64 + svv;
            Ws[(skc + 0) * WSS + vv] = wq[rep].x;
            Ws[(skc + 1) * WSS + vv] = wq[rep].y;
            Ws[(skc + 2) * WSS + vv] = wq[rep].z;
            Ws[(skc + 3) * WSS + vv] = wq[rep].w;
        }
        if (t < 128) {
            As[(akq * 4 + 0) * EBM + arow] = fmaxf(aq.x, 0.f);
            As[(akq * 4 + 1) * EBM + arow] = fmaxf(aq.y, 0.f);
            As[(akq * 4 + 2) * EBM + arow] = fmaxf(aq.z, 0.f);
            As[(akq * 4 + 3) * EBM + arow] = fmaxf(aq.w, 0.f);
        }
        __syncthreads();

        // issue next tile's global loads NOW; the 16-k compute below hides them
        if (kt + 1 < 40) {
            const int k0 = (kt + 1) * EBK;
            #pragma unroll
            for (int rep = 0; rep < 4; ++rep)
                wq[rep] = *(const float4*)(W + (size_t)(v0 + rep * 64 + svv) * 1280 + k0 + skc);
            if (t < 128)
                aq = *(const float4*)(enc + (size_t)(bt0 + arow) * 640 + k0 + akq * 4);
        }

        #pragma unroll
        for (int k = 0; k < EBK; ++k) {
            const float4 a0 = *(const float4*)&As[k * EBM + ty * 8];      // broadcast
            const float4 a1 = *(const float4*)&As[k * EBM + ty * 8 + 4];  // broadcast
            const float4 bv = *(const float4*)&Ws[k * WSS + l4];          // 1 KB contiguous
            const float ar[8] = {a0.x, a0.y, a0.z, a0.w, a1.x, a1.y, a1.z, a1.w};
            const float br[4] = {bv.x, bv.y, bv.z, bv.w};
            #pragma unroll
            for (int i = 0; i < 8; ++i)
                #pragma unroll
                for (int j = 0; j < 4; ++j)
                    acc[i][j] = fmaf(ar[i], br[j], acc[i][j]);
        }
    }

    // fold bias (varies over v only)
    {
        const float4 bb = *(const float4*)(bias + v0 + l4);
        #pragma unroll
        for (int i = 0; i < 8; ++i) {
            acc[i][0] += bb.x; acc[i][1] += bb.y; acc[i][2] += bb.z; acc[i][3] += bb.w;
        }
    }

    // ---- Phase B: out = E + P; plain stores, 1 KB contiguous per wave-store ----
    const float* Pb = P + (size_t)b * 65536 + v0 + l4;
    float* ob = out + (size_t)(bt0 + ty * 8) * 65536 + v0 + l4;

    #pragma unroll 4
    for (int u = 0; u < 64; ++u) {
        const float4 p4 = *(const float4*)(Pb + (size_t)u * 1024);
        #pragma unroll
        for (int i = 0; i < 8; ++i) {
            float4 o;
            o.x = acc[i][0] + p4.x;
            o.y = acc[i][1] + p4.y;
            o.z = acc[i][2] + p4.z;
            o.w = acc[i][3] + p4.w;
            *(float4*)(ob + (size_t)i * 65536 + (size_t)u * 1024) = o;
        }
    }
}

__global__ void lengths_kernel(const int* __restrict__ sl,
                               const int* __restrict__ tl,
                               float* __restrict__ out_tail)
{
    const int i = threadIdx.x;
    if (i < 8) {
        out_tail[i]     = (float)sl[i];
        out_tail[8 + i] = (float)tl[i];
    }
}

extern "C" void kernel_launch(void* const* d_in, const int* in_sizes, int n_in,
                              void* d_out, int out_size, void* d_ws, size_t ws_size,
                              hipStream_t stream) {
    const float* enc  = (const float*)d_in[0];   // [8,256,640]
    const int*   sl   = (const int*)d_in[1];     // [8]
    const float* pred = (const float*)d_in[2];   // [8,64,640]
    const int*   tl   = (const int*)d_in[3];     // [8]
    const float* W    = (const float*)d_in[4];   // [1024,1280]
    const float* bias = (const float*)d_in[5];   // [1024]

    float* out = (float*)d_out;
    float* P   = (float*)d_ws;                   // 512*1024 f32 = 2 MB

    // P first (tiny); stream order guarantees P complete before e_fused reads it.
    p_gemm_kernel<<<dim3(16, 8), 256, 0, stream>>>(pred, W, P);

    // 256 blocks = exactly 1/CU; blockIdx.x (vtile) is fixed per XCD under
    // round-robin dispatch -> each XCD L2 holds one 655 KB W-slab + 2 MB P.
    e_fused_kernel<<<dim3(4, 64), 256, 0, stream>>>(enc, W, bias, P, out);

    lengths_kernel<<<1, 64, 0, stream>>>(sl, tl, out + (size_t)131072 * 1024);
}